// Round 1
// baseline (84.467 us; speedup 1.0000x reference)
//
#include <hip/hip_runtime.h>

#define IN_FEATURES 4096
#define OUT_FEATURES 11008
#define KW (IN_FEATURES / 8)           // 512 packed rows along input dim
#define OTILE 128                      // outputs per block (512 B contiguous span)
#define NOTILE (OUT_FEATURES / OTILE)  // 86 output tiles
#define KSPLIT 8                       // k-split across blockIdx.y
#define ROWS_B (KW / KSPLIT)           // 64 rows per block
#define BLOCK 256
#define W 8                            // rows (independent int4 loads) per thread: 128 B/thread

// Replaces the memset node: out[o] = bias[o] - x_sum * zeros[o].
// Each block redundantly computes x_sum (16 KB of x, L2-broadcast) -> no extra sync kernel.
__global__ __launch_bounds__(BLOCK) void q4_init(
    const float* __restrict__ x,
    const float* __restrict__ zeros,
    const float* __restrict__ bias,
    float* __restrict__ out)
{
    __shared__ float part[BLOCK / 64];
    const int tid = threadIdx.x;
    const float4* x4 = (const float4*)x;

    float s = 0.f;
#pragma unroll
    for (int i = 0; i < (IN_FEATURES / 4) / BLOCK; ++i) {   // 4 float4 per thread
        const float4 v = x4[i * BLOCK + tid];
        s += (v.x + v.y) + (v.z + v.w);
    }
#pragma unroll
    for (int off = 32; off > 0; off >>= 1) s += __shfl_down(s, off);
    if ((tid & 63) == 0) part[tid >> 6] = s;
    __syncthreads();
    const float xsum = (part[0] + part[1]) + (part[2] + part[3]);

    const int o = blockIdx.x * BLOCK + tid;                 // 43 * 256 = 11008 exactly
    out[o] = bias[o] - xsum * zeros[o];
}

// Barrier-free, LDS-free streaming matvec over the packed weights.
// Half-wave (32 lanes) reads 512 B contiguous per instruction; 8 loads in flight/thread.
__global__ __launch_bounds__(BLOCK) void q4_main(
    const float* __restrict__ x,
    const int* __restrict__ qw,
    const float* __restrict__ scales,
    float* __restrict__ out)
{
    const int tid  = threadIdx.x;
    const int og   = tid & 31;          // 32 output groups x 4 cols = 128 outputs = 512 B
    const int half = (tid >> 5) & 1;    // two row-halves per wave
    const int wv   = tid >> 6;          // wave id 0..3

    const int o4 = blockIdx.x * OTILE + og * 4;
    const int r0 = blockIdx.y * ROWS_B + wv * 16 + half * 8;   // this thread's 8 rows

    // Issue all 8 qweight loads up front (independent, all in flight).
    const int* qp = qw + (long)r0 * OUT_FEATURES + o4;
    int4 qv[W];
#pragma unroll
    for (int i = 0; i < W; ++i)
        qv[i] = *(const int4*)(qp + (long)i * OUT_FEATURES);

    // x via broadcast global loads: 32 lanes/same address -> one 16 B request, L1-hot.
    const float4* x4 = (const float4*)x;
    float acc0 = 0.f, acc1 = 0.f, acc2 = 0.f, acc3 = 0.f;
#pragma unroll
    for (int i = 0; i < W; ++i) {
        const float4 xa = x4[(r0 + i) * 2 + 0];
        const float4 xb = x4[(r0 + i) * 2 + 1];
        const float xv[8] = {xa.x, xa.y, xa.z, xa.w, xb.x, xb.y, xb.z, xb.w};
        const unsigned qx = (unsigned)qv[i].x, qy = (unsigned)qv[i].y,
                       qz = (unsigned)qv[i].z, qt = (unsigned)qv[i].w;
#pragma unroll
        for (int n = 0; n < 8; ++n) {
            const float xvn = xv[n];
            acc0 += xvn * (float)((qx >> (4 * n)) & 0xFu);
            acc1 += xvn * (float)((qy >> (4 * n)) & 0xFu);
            acc2 += xvn * (float)((qz >> (4 * n)) & 0xFu);
            acc3 += xvn * (float)((qt >> (4 * n)) & 0xFu);
        }
    }

    // Combine the two row-halves of the wave; lanes 0-31 then own the totals.
    acc0 += __shfl_xor(acc0, 32);
    acc1 += __shfl_xor(acc1, 32);
    acc2 += __shfl_xor(acc2, 32);
    acc3 += __shfl_xor(acc3, 32);

    if ((tid & 32) == 0) {
        const float4 sc = *(const float4*)(scales + o4);
        atomicAdd(out + o4 + 0, acc0 * sc.x);
        atomicAdd(out + o4 + 1, acc1 * sc.y);
        atomicAdd(out + o4 + 2, acc2 * sc.z);
        atomicAdd(out + o4 + 3, acc3 * sc.w);
    }
}

extern "C" void kernel_launch(void* const* d_in, const int* in_sizes, int n_in,
                              void* d_out, int out_size, void* d_ws, size_t ws_size,
                              hipStream_t stream) {
    const float* x      = (const float*)d_in[0];
    const int*   qw     = (const int*)d_in[1];
    const float* scales = (const float*)d_in[2];
    const float* zeros  = (const float*)d_in[3];
    const float* bias   = (const float*)d_in[4];
    float* out = (float*)d_out;

    q4_init<<<dim3(OUT_FEATURES / BLOCK), BLOCK, 0, stream>>>(x, zeros, bias, out);
    q4_main<<<dim3(NOTILE, KSPLIT), BLOCK, 0, stream>>>(x, qw, scales, out);
}

// Round 3
// 80.260 us; speedup vs baseline: 1.0524x; 1.0524x over previous
//
#include <hip/hip_runtime.h>

#define IN_FEATURES 4096
#define OUT_FEATURES 11008
#define KW (IN_FEATURES / 8)          // 512 packed rows along input dim
#define OTILE 32                      // outputs per block
#define NBLK (OUT_FEATURES / OTILE)   // 344 blocks
#define BLOCK 512
#define NWAVE (BLOCK / 64)            // 8 waves
#define KGROUPS (BLOCK / 8)           // 64 k-groups of 8 output-lanes
#define W (KW / KGROUPS)              // 8 rows per thread (8 independent 16B loads)

// One kernel, one dispatch: full-K per block -> no atomics, no out-memset,
// bias/zeros epilogue fused (x_sum recomputed per block from L2-hot x).
__global__ __launch_bounds__(BLOCK) void q4_matvec(
    const float* __restrict__ x,
    const int* __restrict__ qw,
    const float* __restrict__ scales,
    const float* __restrict__ zeros,
    const float* __restrict__ bias,
    float* __restrict__ out)
{
    __shared__ float red[NWAVE][OTILE];
    __shared__ float xred[NWAVE];

    const int tid = threadIdx.x;
    const int og  = tid & 7;           // 8 output groups x 4 cols = 32 outputs
    const int kg  = tid >> 3;          // 0..63 k-groups
    const int o4  = blockIdx.x * OTILE + og * 4;

    // ---- all 8 qweight loads issued up front (independent, in flight) ----
    // row for load i: r = kg + i*KGROUPS -> per wave-instruction, 8 consecutive
    // rows x 128 B contiguous segments (8 og-lanes x 16 B).
    const int* qp = qw + (long)kg * OUT_FEATURES + o4;
    int4 qv[W];
#pragma unroll
    for (int i = 0; i < W; ++i)
        qv[i] = *(const int4*)(qp + (long)i * KGROUPS * OUT_FEATURES);

    // ---- unpack + MAC; x via broadcast loads (16 KB, L1/L2-hot) ----
    // Even/odd nibble split: one and/shift pair per word, then byte-extracts
    // that pattern-match to v_cvt_f32_ubyte{0..3} (1 op per nibble->float).
    const float4* x4 = (const float4*)x;
    float acc0 = 0.f, acc1 = 0.f, acc2 = 0.f, acc3 = 0.f;
#pragma unroll
    for (int i = 0; i < W; ++i) {
        const int r = kg + i * KGROUPS;
        const float4 xa = x4[r * 2 + 0];
        const float4 xb = x4[r * 2 + 1];
        const unsigned q0 = (unsigned)qv[i].x, q1 = (unsigned)qv[i].y,
                       q2 = (unsigned)qv[i].z, q3 = (unsigned)qv[i].w;

        {   const unsigned e = q0 & 0x0F0F0F0Fu, o = (q0 >> 4) & 0x0F0F0F0Fu;
            acc0 += xa.x * (float)(e & 0xFFu);
            acc0 += xa.y * (float)(o & 0xFFu);
            acc0 += xa.z * (float)((e >> 8) & 0xFFu);
            acc0 += xa.w * (float)((o >> 8) & 0xFFu);
            acc0 += xb.x * (float)((e >> 16) & 0xFFu);
            acc0 += xb.y * (float)((o >> 16) & 0xFFu);
            acc0 += xb.z * (float)((e >> 24) & 0xFFu);
            acc0 += xb.w * (float)(o >> 24); }
        {   const unsigned e = q1 & 0x0F0F0F0Fu, o = (q1 >> 4) & 0x0F0F0F0Fu;
            acc1 += xa.x * (float)(e & 0xFFu);
            acc1 += xa.y * (float)(o & 0xFFu);
            acc1 += xa.z * (float)((e >> 8) & 0xFFu);
            acc1 += xa.w * (float)((o >> 8) & 0xFFu);
            acc1 += xb.x * (float)((e >> 16) & 0xFFu);
            acc1 += xb.y * (float)((o >> 16) & 0xFFu);
            acc1 += xb.z * (float)((e >> 24) & 0xFFu);
            acc1 += xb.w * (float)(o >> 24); }
        {   const unsigned e = q2 & 0x0F0F0F0Fu, o = (q2 >> 4) & 0x0F0F0F0Fu;
            acc2 += xa.x * (float)(e & 0xFFu);
            acc2 += xa.y * (float)(o & 0xFFu);
            acc2 += xa.z * (float)((e >> 8) & 0xFFu);
            acc2 += xa.w * (float)((o >> 8) & 0xFFu);
            acc2 += xb.x * (float)((e >> 16) & 0xFFu);
            acc2 += xb.y * (float)((o >> 16) & 0xFFu);
            acc2 += xb.z * (float)((e >> 24) & 0xFFu);
            acc2 += xb.w * (float)(o >> 24); }
        {   const unsigned e = q3 & 0x0F0F0F0Fu, o = (q3 >> 4) & 0x0F0F0F0Fu;
            acc3 += xa.x * (float)(e & 0xFFu);
            acc3 += xa.y * (float)(o & 0xFFu);
            acc3 += xa.z * (float)((e >> 8) & 0xFFu);
            acc3 += xa.w * (float)((o >> 8) & 0xFFu);
            acc3 += xb.x * (float)((e >> 16) & 0xFFu);
            acc3 += xb.y * (float)((o >> 16) & 0xFFu);
            acc3 += xb.z * (float)((e >> 24) & 0xFFu);
            acc3 += xb.w * (float)(o >> 24); }
    }

    // ---- butterfly over tid bits 3..5: sums the wave's 8 k-groups ----
#pragma unroll
    for (int m = 8; m <= 32; m <<= 1) {
        acc0 += __shfl_xor(acc0, m);
        acc1 += __shfl_xor(acc1, m);
        acc2 += __shfl_xor(acc2, m);
        acc3 += __shfl_xor(acc3, m);
    }
    const int lane = tid & 63;
    const int wid  = tid >> 6;
    if (lane < 8) {                    // lane == og here
        red[wid][lane * 4 + 0] = acc0;
        red[wid][lane * 4 + 1] = acc1;
        red[wid][lane * 4 + 2] = acc2;
        red[wid][lane * 4 + 3] = acc3;
    }

    // ---- x-sum pass (L1-hot re-read, 2 float4/thread) ----
    {
        const float4 a = x4[tid];
        const float4 b = x4[tid + BLOCK];
        float xs = (a.x + a.y + a.z + a.w) + (b.x + b.y + b.z + b.w);
#pragma unroll
        for (int off = 32; off > 0; off >>= 1) xs += __shfl_down(xs, off);
        if (lane == 0) xred[wid] = xs;
    }
    __syncthreads();

    // ---- combine waves + fused epilogue, direct store ----
    if (tid < OTILE) {
        float s = 0.f;
#pragma unroll
        for (int g = 0; g < NWAVE; ++g) s += red[g][tid];
        float xsum = 0.f;
#pragma unroll
        for (int g = 0; g < NWAVE; ++g) xsum += xred[g];
        const int o = blockIdx.x * OTILE + tid;
        out[o] = s * scales[o] - xsum * zeros[o] + bias[o];
    }
}

extern "C" void kernel_launch(void* const* d_in, const int* in_sizes, int n_in,
                              void* d_out, int out_size, void* d_ws, size_t ws_size,
                              hipStream_t stream) {
    const float* x      = (const float*)d_in[0];
    const int*   qw     = (const int*)d_in[1];
    const float* scales = (const float*)d_in[2];
    const float* zeros  = (const float*)d_in[3];
    const float* bias   = (const float*)d_in[4];
    float* out = (float*)d_out;

    q4_matvec<<<dim3(NBLK), BLOCK, 0, stream>>>(x, qw, scales, zeros, bias, out);
}